// Round 8
// baseline (839.446 us; speedup 1.0000x reference)
//
#include <hip/hip_runtime.h>
#include <cstdint>
#include <cstddef>

typedef __bf16 bf16x8 __attribute__((ext_vector_type(8)));
typedef float f32x4 __attribute__((ext_vector_type(4)));
typedef unsigned short us16;

__device__ __forceinline__ float lrelu(float v) { return v >= 0.0f ? v : 0.01f * v; }
__device__ __forceinline__ float fsigmoid(float x) {
  x = fminf(fmaxf(x, -30.0f), 30.0f);
  return 1.0f / (1.0f + __expf(-x));
}
__device__ __forceinline__ float ftanh(float x) {
  x = fminf(fmaxf(x, -15.0f), 15.0f);
  float e = __expf(2.0f * x);
  return (e - 1.0f) / (e + 1.0f);
}
__device__ __forceinline__ us16 f2b(float f) {
  unsigned int u = __builtin_bit_cast(unsigned int, f);
  u = (u + 0x7fffu + ((u >> 16) & 1u)) >> 16;
  return (us16)u;
}
__device__ __forceinline__ float b2f(us16 h) {
  unsigned int u = ((unsigned int)h) << 16;
  return __builtin_bit_cast(float, u);
}
__device__ __forceinline__ unsigned pk2(float a, float b) {
  return (unsigned)f2b(a) | ((unsigned)f2b(b) << 16);
}
__device__ __forceinline__ void unp8(int4 v, float* t) {
  unsigned a = (unsigned)v.x, b = (unsigned)v.y, c = (unsigned)v.z, d = (unsigned)v.w;
  t[0] = b2f((us16)(a & 0xffff)); t[1] = b2f((us16)(a >> 16));
  t[2] = b2f((us16)(b & 0xffff)); t[3] = b2f((us16)(b >> 16));
  t[4] = b2f((us16)(c & 0xffff)); t[5] = b2f((us16)(c >> 16));
  t[6] = b2f((us16)(d & 0xffff)); t[7] = b2f((us16)(d >> 16));
}

// ---------------- degree / CSR build ----------------
__global__ void k_deg(const int* __restrict__ dst, int* __restrict__ indeg, int E) {
  int e = blockIdx.x * 256 + threadIdx.x;
  if (e < E) atomicAdd(&indeg[dst[e]], 1);
}

__global__ __launch_bounds__(1024) void k_scan1(const int* __restrict__ v, int* __restrict__ rp,
                                                int* __restrict__ part, float* __restrict__ dis, int n) {
  __shared__ int wsum[16];
  int base = blockIdx.x << 10;
  int t = threadIdx.x, lane = t & 63, wv = t >> 6;
  int val = (base + t < n) ? v[base + t] : 0;
  if (base + t < n) dis[base + t] = rsqrtf((float)(val + 1));
  int s = val;
  #pragma unroll
  for (int off = 1; off < 64; off <<= 1) {
    int u = __shfl_up(s, off);
    if (lane >= off) s += u;
  }
  if (lane == 63) wsum[wv] = s;
  __syncthreads();
  int wadd = 0;
  #pragma unroll
  for (int w = 0; w < 16; ++w) wadd += (w < wv) ? wsum[w] : 0;
  if (base + t < n) rp[base + t] = wadd + s - val;
  if (t == 0) {
    int tot = 0;
    #pragma unroll
    for (int w = 0; w < 16; ++w) tot += wsum[w];
    part[blockIdx.x] = tot;
  }
}

__global__ __launch_bounds__(1024) void k_scan2(int* __restrict__ p, int nc) {
  __shared__ int wsum[16];
  int t = threadIdx.x, lane = t & 63, wv = t >> 6;
  int val = (t < nc) ? p[t] : 0;
  int s = val;
  #pragma unroll
  for (int off = 1; off < 64; off <<= 1) {
    int u = __shfl_up(s, off);
    if (lane >= off) s += u;
  }
  if (lane == 63) wsum[wv] = s;
  __syncthreads();
  int wadd = 0;
  #pragma unroll
  for (int w = 0; w < 16; ++w) wadd += (w < wv) ? wsum[w] : 0;
  if (t < nc) p[t] = wadd + s - val;
}

__global__ void k_scan3(int* __restrict__ rp, const int* __restrict__ part,
                        int* __restrict__ cursor, int n, int total) {
  int i = blockIdx.x * 256 + threadIdx.x;
  if (i < n) {
    int v = rp[i] + part[i >> 10];
    rp[i] = v;
    cursor[i] = v;
  } else if (i == n) {
    rp[n] = total;
  }
}

__global__ void k_fill(const int* __restrict__ src, const int* __restrict__ dst,
                       const float* __restrict__ dis, int* __restrict__ cursor,
                       int* __restrict__ csrc, float* __restrict__ cw, int E) {
  int e = blockIdx.x * 256 + threadIdx.x;
  if (e >= E) return;
  int s = src[e], d = dst[e];
  int pos = atomicAdd(&cursor[d], 1);
  csrc[pos] = s;
  cw[pos] = dis[s] * dis[d];
}

// ---------------- repack ----------------
__global__ void k_cast(const float* __restrict__ in, us16* __restrict__ out, int n) {
  int i = (blockIdx.x * 256 + threadIdx.x) * 4;
  if (i >= n) return;
  float4 v = *(const float4*)(in + i);
  *(ushort4*)(out + i) = make_ushort4(f2b(v.x), f2b(v.y), f2b(v.z), f2b(v.w));
}

__global__ void k_prepw(const float* __restrict__ Wih1, const float* __restrict__ Whh1,
                        const float* __restrict__ Wih2, const float* __restrict__ Whh2,
                        const float* __restrict__ Wp1, const float* __restrict__ Wp2,
                        const float* __restrict__ Wc1, const float* __restrict__ Wc2,
                        us16* __restrict__ Wih1b, us16* __restrict__ Whh1b,
                        us16* __restrict__ Wih2b, us16* __restrict__ Whh2b,
                        us16* __restrict__ WtP1, us16* __restrict__ WtP2,
                        us16* __restrict__ WtC1, us16* __restrict__ WtC2) {
  int e = blockIdx.x * 256 + threadIdx.x;
  if (e < 196608) { Wih1b[e] = f2b(Wih1[e]); return; }
  e -= 196608;
  if (e < 196608) { Whh1b[e] = f2b(Whh1[e]); return; }
  e -= 196608;
  if (e < 49152) { Wih2b[e] = f2b(Wih2[e]); return; }
  e -= 49152;
  if (e < 49152) { Whh2b[e] = f2b(Whh2[e]); return; }
  e -= 49152;
  if (e < 32768) { int r = e & 127, c = e >> 7; WtP1[e] = f2b(Wp1[(size_t)r * 256 + c]); return; }
  e -= 32768;
  if (e < 32768) { int r = e & 255, c = e >> 8; WtP2[e] = f2b(Wp2[(size_t)r * 128 + c]); return; }
  e -= 32768;
  if (e < 32768) { int r = e & 127, c = e >> 7; WtC1[e] = f2b(Wc1[(size_t)r * 256 + c]); return; }
  e -= 32768;
  if (e < 32768) { int r = e & 255, c = e >> 8; WtC2[e] = f2b(Wc2[(size_t)r * 128 + c]); }
}

// ---------------- bf16 MFMA GEMM, weights-resident: C = act(A @ Bt^T + bias) ----------------
// Block 128 rows x 128 cols, 4 waves (2x2), wave tile 64x64. B-strip loaded to LDS ONCE
// (xor-swizzled), A-frags gathered directly from global. No barriers in K-loop.
template<int ACT, int BIAS, int K>
__global__ __launch_bounds__(256) void k_mm(const us16* __restrict__ A,
                                            const us16* __restrict__ Bt,
                                            const float* __restrict__ bias,
                                            us16* __restrict__ Cb,
                                            int M, int Nc, int ny) {
  __shared__ __align__(16) us16 wl[128 * K];
  const int bm = (blockIdx.x / ny) * 128;
  const int bn = (blockIdx.x % ny) * 128;
  const int tid = threadIdx.x;
  const int lane = tid & 63;
  const int wave = tid >> 6;
  const int wm = (wave >> 1) * 64;
  const int wn = (wave & 1) * 64;
  const int lr = lane & 15;
  const int lk = lane >> 4;

  // stage B-strip (128 cols x K) into LDS, swizzled
  constexpr int CHB = K / 8;
  #pragma unroll
  for (int it = 0; it < (128 * CHB) / 256; ++it) {
    int idx = it * 256 + tid;
    int cir = idx & (CHB - 1);
    int col = idx / CHB;
    int4 v = *(const int4*)(Bt + (size_t)(bn + col) * K + cir * 8);
    size_t db = (((size_t)col * K + cir * 8) * 2) ^ (size_t)((col & 7) << 4);
    *(int4*)((char*)wl + db) = v;
  }
  __syncthreads();

  const us16* ap[4];
  #pragma unroll
  for (int i = 0; i < 4; ++i) {
    int r = bm + wm + i * 16 + lr; if (r >= M) r = M - 1;
    ap[i] = A + (size_t)r * K + lk * 8;
  }
  f32x4 acc[4][4] = {};
  #pragma unroll
  for (int kk = 0; kk < K / 32; ++kk) {
    bf16x8 af[4], bq[4];
    #pragma unroll
    for (int i = 0; i < 4; ++i) af[i] = *(const bf16x8*)(ap[i] + kk * 32);
    #pragma unroll
    for (int j = 0; j < 4; ++j) {
      int col = wn + j * 16 + lr;
      size_t db = (((size_t)col * K + kk * 32 + lk * 8) * 2) ^ (size_t)((col & 7) << 4);
      bq[j] = *(const bf16x8*)((const char*)wl + db);
    }
    #pragma unroll
    for (int i = 0; i < 4; ++i)
      #pragma unroll
      for (int j = 0; j < 4; ++j)
        acc[i][j] = __builtin_amdgcn_mfma_f32_16x16x32_bf16(af[i], bq[j], acc[i][j], 0, 0, 0);
  }
  float bb[4];
  #pragma unroll
  for (int j = 0; j < 4; ++j) bb[j] = BIAS ? bias[bn + wn + j * 16 + lr] : 0.0f;
  #pragma unroll
  for (int i = 0; i < 4; ++i) {
    #pragma unroll
    for (int q = 0; q < 4; ++q) {
      int row = bm + wm + i * 16 + lk * 4 + q;
      if (row < M) {
        #pragma unroll
        for (int j = 0; j < 4; ++j) {
          int col = bn + wn + j * 16 + lr;
          float v = acc[i][j][q] + bb[j];
          if (ACT) v = lrelu(v);
          Cb[(size_t)row * Nc + col] = f2b(v);
        }
      }
    }
  }
}

// ---------------- CSR aggregation, F=128 ----------------
template<int ACT>
__global__ __launch_bounds__(256) void k_agg128(const us16* __restrict__ hw, const int* __restrict__ rp,
                                                const int* __restrict__ csrc, const float* __restrict__ cw,
                                                const float* __restrict__ dis, const float* __restrict__ bias,
                                                us16* __restrict__ outp, int M) {
  int node = blockIdx.x * 16 + (threadIdx.x >> 4);
  int l = threadIdx.x & 15;
  if (node >= M) return;
  const us16* base = hw + l * 8;
  float acc[8], t0[8], t1[8], t2[8], t3[8];
  float dn = dis[node];
  float sw = dn * dn;
  {
    int4 v = *(const int4*)(base + (size_t)node * 128);
    unp8(v, t0);
    #pragma unroll
    for (int j = 0; j < 8; ++j) acc[j] = t0[j] * sw;
  }
  int e = rp[node], e1 = rp[node + 1];
  for (; e + 4 <= e1; e += 4) {
    int s0 = csrc[e], s1 = csrc[e + 1], s2 = csrc[e + 2], s3 = csrc[e + 3];
    float w0 = cw[e], w1 = cw[e + 1], w2 = cw[e + 2], w3 = cw[e + 3];
    int4 v0 = *(const int4*)(base + (size_t)s0 * 128);
    int4 v1 = *(const int4*)(base + (size_t)s1 * 128);
    int4 v2 = *(const int4*)(base + (size_t)s2 * 128);
    int4 v3 = *(const int4*)(base + (size_t)s3 * 128);
    unp8(v0, t0); unp8(v1, t1); unp8(v2, t2); unp8(v3, t3);
    #pragma unroll
    for (int j = 0; j < 8; ++j) acc[j] = fmaf(w0, t0[j], acc[j]);
    #pragma unroll
    for (int j = 0; j < 8; ++j) acc[j] = fmaf(w1, t1[j], acc[j]);
    #pragma unroll
    for (int j = 0; j < 8; ++j) acc[j] = fmaf(w2, t2[j], acc[j]);
    #pragma unroll
    for (int j = 0; j < 8; ++j) acc[j] = fmaf(w3, t3[j], acc[j]);
  }
  for (; e < e1; ++e) {
    int s0 = csrc[e];
    float w0 = cw[e];
    int4 v0 = *(const int4*)(base + (size_t)s0 * 128);
    unp8(v0, t0);
    #pragma unroll
    for (int j = 0; j < 8; ++j) acc[j] = fmaf(w0, t0[j], acc[j]);
  }
  if (ACT) {
    float4 b0 = *(const float4*)(bias + l * 8);
    float4 b1 = *(const float4*)(bias + l * 8 + 4);
    float bb[8] = {b0.x, b0.y, b0.z, b0.w, b1.x, b1.y, b1.z, b1.w};
    #pragma unroll
    for (int j = 0; j < 8; ++j) acc[j] = lrelu(acc[j] + bb[j]);
  }
  int4 o;
  o.x = (int)pk2(acc[0], acc[1]);
  o.y = (int)pk2(acc[2], acc[3]);
  o.z = (int)pk2(acc[4], acc[5]);
  o.w = (int)pk2(acc[6], acc[7]);
  *(int4*)(outp + (size_t)node * 128 + l * 8) = o;
}

// ---------------- fused GRU cell, weights-resident role-split (MFMA) ----------------
// Block 512 thr = 8 waves = 4 row-pairs x {gi, gh}. 128 rows x 32 gate-cols.
// All 6 weight slabs (6 x 32 x H) live in LDS for the whole block (xor-swizzled);
// x/h fragments gathered directly from global. ZERO barriers in the K-loop.
// Epilogue: gh waves publish accs via LDS (reusing weight space); gi waves combine.
template<int H, int WB, int PH>
__global__ __launch_bounds__(512) void k_fgru(const us16* __restrict__ xb, const us16* __restrict__ hb,
                                              const us16* __restrict__ Wih, const us16* __restrict__ Whh,
                                              const float* __restrict__ bih, const float* __restrict__ bhh,
                                              float* __restrict__ emb, us16* __restrict__ embb,
                                              const float* __restrict__ Wpost, const float* __restrict__ bpost,
                                              float* __restrict__ outv, int M, int ny) {
  __shared__ __align__(16) us16 wl[192 * H];  // 6 gates x 32 cols x H (96KB @256, 48KB @128)
  const int nwg = gridDim.x;
  int bid = blockIdx.x;
  {  // bijective XCD-chunked remap
    int q8 = nwg >> 3, r8 = nwg & 7;
    int xc = bid & 7, ix = bid >> 3;
    bid = (xc < r8 ? xc * (q8 + 1) : r8 * (q8 + 1) + (xc - r8) * q8) + ix;
  }
  const int bn = (bid % ny) * 32;
  const int bm = (bid / ny) * 128;
  const int tid = threadIdx.x;
  const int lane = tid & 63, wave = tid >> 6;
  const int pair = wave >> 1;   // 0..3 -> 32-row group
  const int role = wave & 1;    // 0 = gi (x, Wih), 1 = gh (h, Whh)
  const int lr = lane & 15, lk = lane >> 4;

  // ---- stage all 6 weight slabs into LDS once (swizzled) ----
  constexpr int CHR = H / 8;  // 16B chunks per col-row
  #pragma unroll
  for (int it = 0; it < (192 * CHR) / 512; ++it) {
    int idx = it * 512 + tid;
    int cir = idx & (CHR - 1);
    int row = idx / CHR;        // 0..191: g6 = row>>5, col = row&31
    int g6 = row >> 5, c = row & 31;
    const us16* W = (g6 < 3) ? Wih : Whh;
    int gg = (g6 < 3) ? g6 : g6 - 3;
    int4 v = *(const int4*)(W + (size_t)(gg * H + bn + c) * H + cir * 8);
    size_t db = (((size_t)row * H + cir * 8) * 2) ^ (size_t)((c & 7) << 4);
    *(int4*)((char*)wl + db) = v;
  }
  __syncthreads();

  // ---- K-loop: barrier-free; A direct from global, B from resident LDS ----
  const us16* abase = role ? hb : xb;
  int ra0 = bm + pair * 32 + lr;      if (ra0 >= M) ra0 = M - 1;
  int ra1 = bm + pair * 32 + 16 + lr; if (ra1 >= M) ra1 = M - 1;
  const us16* ap0 = abase + (size_t)ra0 * H + lk * 8;
  const us16* ap1 = abase + (size_t)ra1 * H + lk * 8;

  f32x4 acc[3][2][2] = {};
  #pragma unroll
  for (int t = 0; t < H / 32; ++t) {
    bf16x8 a0 = *(const bf16x8*)(ap0 + t * 32);
    bf16x8 a1 = *(const bf16x8*)(ap1 + t * 32);
    #pragma unroll
    for (int g = 0; g < 3; ++g) {
      int g6 = role * 3 + g;
      int c0 = lr, c1 = 16 + lr;
      size_t db0 = (((size_t)(g6 * 32 + c0) * H + t * 32 + lk * 8) * 2) ^ (size_t)((c0 & 7) << 4);
      size_t db1 = (((size_t)(g6 * 32 + c1) * H + t * 32 + lk * 8) * 2) ^ (size_t)((c1 & 7) << 4);
      bf16x8 b0 = *(const bf16x8*)((const char*)wl + db0);
      bf16x8 b1 = *(const bf16x8*)((const char*)wl + db1);
      acc[g][0][0] = __builtin_amdgcn_mfma_f32_16x16x32_bf16(a0, b0, acc[g][0][0], 0, 0, 0);
      acc[g][0][1] = __builtin_amdgcn_mfma_f32_16x16x32_bf16(a0, b1, acc[g][0][1], 0, 0, 0);
      acc[g][1][0] = __builtin_amdgcn_mfma_f32_16x16x32_bf16(a1, b0, acc[g][1][0], 0, 0, 0);
      acc[g][1][1] = __builtin_amdgcn_mfma_f32_16x16x32_bf16(a1, b1, acc[g][1][1], 0, 0, 0);
    }
  }

  // ---- exchange (reuses weight LDS) + epilogue ----
  __syncthreads();
  float* xch = (float*)&wl[0];  // 48KB needed; wl >= 48KB for both H
  if (role) {
    #pragma unroll
    for (int g = 0; g < 3; ++g)
      #pragma unroll
      for (int i = 0; i < 2; ++i)
        #pragma unroll
        for (int j = 0; j < 2; ++j)
          *(f32x4*)&xch[((((pair * 3 + g) * 2 + i) * 2 + j) * 64 + lane) * 4] = acc[g][i][j];
  }
  __syncthreads();
  if (!role) {
    float part[2][4] = {};
    #pragma unroll
    for (int j = 0; j < 2; ++j) {
      int col = bn + j * 16 + lr;
      float bir = bih[col], biz = bih[H + col], bin = bih[2 * H + col];
      float bhr = bhh[col], bhz = bhh[H + col], bhn = bhh[2 * H + col];
      float wps = 0.0f;
      if (PH) wps = Wpost[2 * col] + Wpost[2 * col + 1];
      #pragma unroll
      for (int i = 0; i < 2; ++i) {
        f32x4 gr_ = *(const f32x4*)&xch[((((pair * 3 + 0) * 2 + i) * 2 + j) * 64 + lane) * 4];
        f32x4 gz_ = *(const f32x4*)&xch[((((pair * 3 + 1) * 2 + i) * 2 + j) * 64 + lane) * 4];
        f32x4 gn_ = *(const f32x4*)&xch[((((pair * 3 + 2) * 2 + i) * 2 + j) * 64 + lane) * 4];
        #pragma unroll
        for (int q = 0; q < 4; ++q) {
          int row = bm + pair * 32 + i * 16 + lk * 4 + q;
          if (row < M) {
            float r = fsigmoid(acc[0][i][j][q] + bir + gr_[q] + bhr);
            float z = fsigmoid(acc[1][i][j][q] + biz + gz_[q] + bhz);
            float n = ftanh(acc[2][i][j][q] + bin + r * (gn_[q] + bhn));
            float hv = b2f(hb[(size_t)row * H + col]);
            float o = (1.0f - z) * n + z * hv;
            emb[(size_t)row * H + col] = o;
            if (WB) embb[(size_t)row * H + col] = f2b(o);
            if (PH) part[i][q] += o * wps;
          }
        }
      }
    }
    if (PH) {
      float bsum = bpost[0] + bpost[1];
      #pragma unroll
      for (int i = 0; i < 2; ++i)
        #pragma unroll
        for (int q = 0; q < 4; ++q) {
          float v = part[i][q];
          v += __shfl_xor(v, 1); v += __shfl_xor(v, 2);
          v += __shfl_xor(v, 4); v += __shfl_xor(v, 8);
          int row = bm + pair * 32 + i * 16 + lk * 4 + q;
          if (lr == 0 && row < M)
            atomicAdd(&outv[row], v + (bn == 0 ? bsum : 0.0f));
        }
    }
  }
}

extern "C" void kernel_launch(void* const* d_in, const int* in_sizes, int n_in,
                              void* d_out, int out_size, void* d_ws, size_t ws_size,
                              hipStream_t stream) {
  const float* x     = (const float*)d_in[0];
  const int*   ei    = (const int*)d_in[1];
  const float* prev0 = (const float*)d_in[2];
  const float* prev1 = (const float*)d_in[3];
  const float* Wp1   = (const float*)d_in[4];
  const float* bp1   = (const float*)d_in[5];
  const float* Wp2   = (const float*)d_in[6];
  const float* bp2   = (const float*)d_in[7];
  const float* Wc1   = (const float*)d_in[8];
  const float* bc1   = (const float*)d_in[9];
  const float* Wc2   = (const float*)d_in[10];
  const float* bc2   = (const float*)d_in[11];
  const float* Wih1  = (const float*)d_in[12];
  const float* Whh1  = (const float*)d_in[13];
  const float* bih1  = (const float*)d_in[14];
  const float* bhh1  = (const float*)d_in[15];
  const float* Wih2  = (const float*)d_in[16];
  const float* Whh2  = (const float*)d_in[17];
  const float* bih2  = (const float*)d_in[18];
  const float* bhh2  = (const float*)d_in[19];
  const float* Wpost = (const float*)d_in[20];
  const float* bpost = (const float*)d_in[21];

  const int N = in_sizes[0] / 128;   // 100000
  const int E = in_sizes[1] / 2;     // 1600000
  const int* srcp = ei;
  const int* dstp = ei + E;

  char* wsb = (char*)d_ws;
  size_t off = 0;
  auto alloc = [&](size_t bytes) -> void* {
    void* p = wsb + off;
    off = (off + bytes + 255) & ~(size_t)255;
    return p;
  };
  float* dis    = (float*)alloc((size_t)N * 4);
  int*   indeg  = (int*)alloc((size_t)N * 4);
  int*   rp     = (int*)alloc((size_t)(N + 1) * 4);
  int*   part   = (int*)alloc((size_t)1024 * 4);
  int*   cursor = (int*)alloc((size_t)N * 4);
  int*   csrc   = (int*)alloc((size_t)E * 4);
  float* cw     = (float*)alloc((size_t)E * 4);
  us16* xb    = (us16*)alloc((size_t)N * 128 * 2);
  us16* p0b   = (us16*)alloc((size_t)N * 256 * 2);
  us16* p1b   = (us16*)alloc((size_t)N * 128 * 2);
  us16* WtP1  = (us16*)alloc((size_t)256 * 128 * 2);
  us16* WtP2  = (us16*)alloc((size_t)128 * 256 * 2);
  us16* WtC1  = (us16*)alloc((size_t)256 * 128 * 2);
  us16* WtC2  = (us16*)alloc((size_t)128 * 256 * 2);
  us16* Wih1b = (us16*)alloc((size_t)768 * 256 * 2);
  us16* Whh1b = (us16*)alloc((size_t)768 * 256 * 2);
  us16* Wih2b = (us16*)alloc((size_t)384 * 128 * 2);
  us16* Whh2b = (us16*)alloc((size_t)384 * 128 * 2);
  us16* bufA  = (us16*)alloc((size_t)N * 256 * 2);
  us16* bufB  = (us16*)alloc((size_t)N * 128 * 2);
  us16* bufD  = (us16*)alloc((size_t)N * 128 * 2);
  us16* emb0b = (us16*)alloc((size_t)N * 256 * 2);
  (void)ws_size; (void)n_in; (void)out_size;

  float* outv = (float*)d_out;
  float* emb0 = outv + N;
  float* emb1 = emb0 + (size_t)N * 256;

  auto cg = [](long n) { return (unsigned)((n / 4 + 255) / 256); };

  // zero the post-head accumulator
  hipMemsetAsync(outv, 0, (size_t)N * 4, stream);

  // activation casts + fused weight prep
  k_cast<<<cg((long)N * 128), 256, 0, stream>>>(x, xb, N * 128);
  k_cast<<<cg((long)N * 256), 256, 0, stream>>>(prev0, p0b, N * 256);
  k_cast<<<cg((long)N * 128), 256, 0, stream>>>(prev1, p1b, N * 128);
  k_prepw<<<2432, 256, 0, stream>>>(Wih1, Whh1, Wih2, Whh2, Wp1, Wp2, Wc1, Wc2,
                                    Wih1b, Whh1b, Wih2b, Whh2b, WtP1, WtP2, WtC1, WtC2);

  // CSR build
  hipMemsetAsync(indeg, 0, (size_t)N * 4, stream);
  k_deg<<<(E + 255) / 256, 256, 0, stream>>>(dstp, indeg, E);
  const int NC = (N + 1023) / 1024;  // 98
  k_scan1<<<NC, 1024, 0, stream>>>(indeg, rp, part, dis, N);
  k_scan2<<<1, 1024, 0, stream>>>(part, NC);
  k_scan3<<<(N + 256) / 256, 256, 0, stream>>>(rp, part, cursor, N, E);
  k_fill<<<(E + 255) / 256, 256, 0, stream>>>(srcp, dstp, dis, cursor, csrc, cw, E);

  const int MB = (N + 127) / 128;   // 782
  const int AB = (N + 15) / 16;     // 6250

  // preprocess MLP (weights-resident GEMMs)
  k_mm<1, 1, 128><<<MB * 2, 256, 0, stream>>>(xb, WtP1, bp1, bufA, N, 256, 2);
  k_mm<1, 1, 256><<<MB, 256, 0, stream>>>(bufA, WtP2, bp2, bufB, N, 128, 1);
  // GCN1: aggregate FIRST (linearity), then linear+bias+leaky
  k_agg128<0><<<AB, 256, 0, stream>>>(bufB, rp, csrc, cw, dis, nullptr, bufD, N);
  k_mm<1, 1, 128><<<MB * 2, 256, 0, stream>>>(bufD, WtC1, bc1, bufA, N, 256, 2);
  // GRU1 fused (weights-resident, barrier-free K-loop)
  k_fgru<256, 1, 0><<<MB * 8, 512, 0, stream>>>(bufA, p0b, Wih1b, Whh1b, bih1, bhh1,
                                                emb0, emb0b, nullptr, nullptr, nullptr, N, 8);
  // GCN2: linear first (256->128), then aggregate with bias+leaky
  k_mm<0, 0, 256><<<MB, 256, 0, stream>>>(emb0b, WtC2, nullptr, bufB, N, 128, 1);
  k_agg128<1><<<AB, 256, 0, stream>>>(bufB, rp, csrc, cw, dis, bc2, bufD, N);
  // GRU2 fused + folded post-head
  k_fgru<128, 0, 1><<<MB * 4, 512, 0, stream>>>(bufD, p1b, Wih2b, Whh2b, bih2, bhh2,
                                                emb1, nullptr, Wpost, bpost, outv, N, 4);
}